// Round 1
// baseline (231.489 us; speedup 1.0000x reference)
//
#include <hip/hip_runtime.h>
#include <hip/hip_bf16.h>

// Problem constants
constexpr int Bb = 8, Nn = 4096, Ss = 1024;
constexpr int D1 = 128, D2 = 256, KIN = 384, OC = 256;
constexpr int L = Bb * Nn;             // 32768 rows
constexpr float BN_EPS = 1e-5f;

typedef __attribute__((ext_vector_type(4))) float floatx4;
typedef __attribute__((ext_vector_type(8))) __bf16 bf16x8;

#define DEV __device__ __forceinline__

DEV float bf2f(unsigned short u) {
    union { unsigned int i; float f; } v; v.i = ((unsigned int)u) << 16; return v.f;
}
DEV unsigned short f2bf(float f) {
    union { float f; unsigned int i; } v; v.f = f;
    unsigned int x = v.i;
    return (unsigned short)((x + 0x7FFFu + ((x >> 16) & 1u)) >> 16);  // RNE
}
// Fast tanh-form gelu: x*sigmoid(2u), u = sqrt(2/pi)*(x+0.044715x^3).
DEV float gelu_f(float x) {
    float u = x * (0.7978845608f + 0.0356774081f * x * x);
    float t = __expf(-2.0f * u);
    return x * __builtin_amdgcn_rcpf(1.0f + t);
}

// Per-block dtype probe (f32 low-halves are mantissa junk; bf16 pairs are sane).
DEV bool probe_isf(const unsigned int* __restrict__ w, int tid) {
    unsigned int lo = w[tid & 63] & 0xFFFFu;
    int e = (int)((lo >> 7) & 0xFF);
    unsigned long long m = __ballot(e >= 100 && e <= 144);
    return __popcll(m) < 48;
}

// Branchless merge of two sorted (asc) top-3 lists; pref=true -> ties keep "a".
DEV void merge3(float& d0, float& d1, float& d2, int& i0, int& i1, int& i2,
                float e0, float e1, float e2, int j0, int j1, int j2, bool pref) {
    float a0 = d0, a1 = d1, a2 = d2; int x0 = i0, x1 = i1, x2 = i2;
    float b0 = e0, b1 = e1;          int y0 = j0, y1 = j1;
    bool t = pref ? (a0 <= b0) : (a0 < b0);
    d0 = t ? a0 : b0; i0 = t ? x0 : y0;
    a0 = t ? a1 : a0; x0 = t ? x1 : x0;
    a1 = t ? a2 : a1; x1 = t ? x2 : x1;
    b0 = t ? b0 : b1; y0 = t ? y0 : y1;
    b1 = t ? b1 : e2; y1 = t ? y1 : j2;
    t = pref ? (a0 <= b0) : (a0 < b0);
    d1 = t ? a0 : b0; i1 = t ? x0 : y0;
    a0 = t ? a1 : a0; x0 = t ? x1 : x0;
    b0 = t ? b0 : b1; y0 = t ? y0 : y1;
    t = pref ? (a0 <= b0) : (a0 < b0);
    d2 = t ? a0 : b0; i2 = t ? x0 : y0;
}

// ---------------- launch 1: zero-stats | prep-weights | 3-NN ----------------
// blocks [0,6): zero stats. blocks [6,902): weights->bf16. blocks [902,1926):
// 32 queries each, 8 lanes/query + shfl_xor merge; results to nn_idx/nn_w.
__global__ __launch_bounds__(256) void k_front(const void* __restrict__ xyz1_,
                                               const void* __restrict__ xyz2_,
                                               const void* __restrict__ w0_,
                                               const void* __restrict__ w1_,
                                               const void* __restrict__ w2_,
                                               unsigned short* __restrict__ Wdst,
                                               float* __restrict__ stats,
                                               int* __restrict__ dflag,
                                               int* __restrict__ nn_idx,
                                               float* __restrict__ nn_w) {
    int tid = threadIdx.x;
    int bid = blockIdx.x;
    bool isf = probe_isf((const unsigned int*)xyz1_, tid);

    if (bid < 6) {
        stats[bid * 256 + tid] = 0.0f;
        if (bid == 0 && tid == 0) *dflag = isf ? 1 : 0;
        return;
    }
    if (bid < 902) {
        int i = (bid - 6) * 256 + tid;
        const void* src; int off;
        if (i < 98304)       { src = w0_; off = i; }
        else if (i < 163840) { src = w1_; off = i - 98304; }
        else                 { src = w2_; off = i - 163840; }
        Wdst[i] = isf ? f2bf(((const float*)src)[off]) : ((const unsigned short*)src)[off];
        return;
    }

    __shared__ alignas(16) float s4[Ss * 4 + 32];
    int bn0 = (bid - 902) * 32;
    int b = bn0 >> 12;

    if (isf) {
        const float* p2 = (const float*)xyz2_ + (size_t)b * Ss * 3;
        for (int i = tid; i < Ss * 3; i += 256) {
            int s = i / 3, k = i - s * 3;
            s4[s * 4 + k + ((s >> 7) << 2)] = p2[i];
        }
    } else {
        const unsigned short* p2 = (const unsigned short*)xyz2_ + (size_t)b * Ss * 3;
        for (int i = tid; i < Ss * 3; i += 256) {
            int s = i / 3, k = i - s * 3;
            s4[s * 4 + k + ((s >> 7) << 2)] = bf2f(p2[i]);
        }
    }
    __syncthreads();
    for (int s = tid; s < Ss; s += 256) {
        int a = s * 4 + ((s >> 7) << 2);
        float x = s4[a], y = s4[a + 1], z = s4[a + 2];
        s4[a + 3] = x * x + y * y + z * z;
    }
    __syncthreads();

    int part = tid & 7;
    int bn = bn0 + (tid >> 3);
    float x1, y1, z1;
    if (isf) {
        const float* p1 = (const float*)xyz1_ + (size_t)bn * 3;
        x1 = p1[0]; y1 = p1[1]; z1 = p1[2];
    } else {
        const unsigned short* p1 = (const unsigned short*)xyz1_ + (size_t)bn * 3;
        x1 = bf2f(p1[0]); y1 = bf2f(p1[1]); z1 = bf2f(p1[2]);
    }
    float n1 = x1 * x1 + y1 * y1 + z1 * z1;

    float d0 = 3.4e38f, d1 = 3.4e38f, d2 = 3.4e38f;
    int i0 = 0, i1 = 0, i2 = 0;
    const float* sp = &s4[part * 516];
#pragma unroll 4
    for (int j = 0; j < 128; ++j) {
        float4 qv = *(const float4*)(sp + j * 4);
        float d = n1 + qv.w - 2.0f * (x1 * qv.x + y1 * qv.y + z1 * qv.z);
        int s = part * 128 + j;
        bool c2 = d < d2, c1 = d < d1, c0 = d < d0;
        d2 = c1 ? d1 : (c2 ? d : d2); i2 = c1 ? i1 : (c2 ? s : i2);
        d1 = c0 ? d0 : (c1 ? d : d1); i1 = c0 ? i0 : (c1 ? s : i1);
        d0 = c0 ? d  : d0;            i0 = c0 ? s  : i0;
    }
#pragma unroll
    for (int m = 1; m <= 4; m <<= 1) {
        float e0 = __shfl_xor(d0, m, 64), e1 = __shfl_xor(d1, m, 64), e2 = __shfl_xor(d2, m, 64);
        int   j0 = __shfl_xor(i0, m, 64), j1 = __shfl_xor(i1, m, 64), j2 = __shfl_xor(i2, m, 64);
        bool pref = (part < (part ^ m));
        merge3(d0, d1, d2, i0, i1, i2, e0, e1, e2, j0, j1, j2, pref);
    }
    if (part == 0) {
        float r0 = 1.0f / (d0 + 1e-8f), r1 = 1.0f / (d1 + 1e-8f), r2 = 1.0f / (d2 + 1e-8f);
        float rs = 1.0f / (r0 + r1 + r2);
        nn_idx[bn * 3 + 0] = i0; nn_idx[bn * 3 + 1] = i1; nn_idx[bn * 3 + 2] = i2;
        nn_w[bn * 3 + 0] = r0 * rs; nn_w[bn * 3 + 1] = r1 * rs; nn_w[bn * 3 + 2] = r2 * rs;
    }
}

// ---------------- launch 2: GEMM1 with A built on the fly ----------------
// A[l][c] = c<128 ? points1[l][c] : interp(points2)[l][c-128]; X never materialized.
// points2 is ~8.4 MB -> L2/L3 resident; gathers hit cache after first touch.
__global__ __launch_bounds__(256) void k_gemm1(const void* __restrict__ p1_,
                                               const void* __restrict__ p2_,
                                               const int* __restrict__ nn_idx,
                                               const float* __restrict__ nn_w,
                                               const int* __restrict__ dflag,
                                               const unsigned short* __restrict__ W,
                                               unsigned short* __restrict__ Out,
                                               float* __restrict__ S1, float* __restrict__ S2) {
    __shared__ alignas(16) unsigned short As[64 * 64];
    __shared__ alignas(16) unsigned short Bs[256 * 64];
    __shared__ float sS1[256], sS2[256];

    int tid = threadIdx.x;
    int l0 = blockIdx.x * 64;
    int wn = tid >> 6, lane = tid & 63, quad = lane >> 4, lr = lane & 15;
    bool isf = (*dflag != 0);

    floatx4 acc[4][4];
#pragma unroll
    for (int mi = 0; mi < 4; ++mi)
#pragma unroll
        for (int ni = 0; ni < 4; ++ni) acc[mi][ni] = (floatx4){0.f, 0.f, 0.f, 0.f};

    for (int kc = 0; kc < KIN / 64; ++kc) {
        __syncthreads();
#pragma unroll
        for (int it = 0; it < 2; ++it) {
            int idx = it * 256 + tid, row = idx >> 3, c8 = idx & 7;
            int pt = l0 + row;
            int c0 = kc * 64 + c8 * 8;
            union { uint4 v; unsigned short u[8]; } va;
            if (c0 < D1) {
                if (isf) {
                    const float* p = (const float*)p1_ + (size_t)pt * D1 + c0;
                    float4 f0 = *(const float4*)p;
                    float4 f1 = *(const float4*)(p + 4);
                    va.u[0] = f2bf(f0.x); va.u[1] = f2bf(f0.y); va.u[2] = f2bf(f0.z); va.u[3] = f2bf(f0.w);
                    va.u[4] = f2bf(f1.x); va.u[5] = f2bf(f1.y); va.u[6] = f2bf(f1.z); va.u[7] = f2bf(f1.w);
                } else {
                    va.v = *(const uint4*)((const unsigned short*)p1_ + (size_t)pt * D1 + c0);
                }
            } else {
                int c2 = c0 - D1;
                int b = pt >> 12;
                int j0 = nn_idx[pt * 3], j1 = nn_idx[pt * 3 + 1], j2 = nn_idx[pt * 3 + 2];
                float w0 = nn_w[pt * 3], w1 = nn_w[pt * 3 + 1], w2 = nn_w[pt * 3 + 2];
                if (isf) {
                    const float* base = (const float*)p2_;
                    const float* r0 = base + ((size_t)(b * Ss + j0)) * D2 + c2;
                    const float* r1 = base + ((size_t)(b * Ss + j1)) * D2 + c2;
                    const float* r2 = base + ((size_t)(b * Ss + j2)) * D2 + c2;
#pragma unroll
                    for (int h = 0; h < 2; ++h) {
                        float4 a0 = *(const float4*)(r0 + h * 4);
                        float4 a1 = *(const float4*)(r1 + h * 4);
                        float4 a2 = *(const float4*)(r2 + h * 4);
                        va.u[h * 4 + 0] = f2bf(w0 * a0.x + w1 * a1.x + w2 * a2.x);
                        va.u[h * 4 + 1] = f2bf(w0 * a0.y + w1 * a1.y + w2 * a2.y);
                        va.u[h * 4 + 2] = f2bf(w0 * a0.z + w1 * a1.z + w2 * a2.z);
                        va.u[h * 4 + 3] = f2bf(w0 * a0.w + w1 * a1.w + w2 * a2.w);
                    }
                } else {
                    const unsigned short* base = (const unsigned short*)p2_;
                    uint4 v0 = *(const uint4*)(base + ((size_t)(b * Ss + j0)) * D2 + c2);
                    uint4 v1 = *(const uint4*)(base + ((size_t)(b * Ss + j1)) * D2 + c2);
                    uint4 v2 = *(const uint4*)(base + ((size_t)(b * Ss + j2)) * D2 + c2);
                    const unsigned short* u0 = (const unsigned short*)&v0;
                    const unsigned short* u1 = (const unsigned short*)&v1;
                    const unsigned short* u2 = (const unsigned short*)&v2;
#pragma unroll
                    for (int j = 0; j < 8; ++j)
                        va.u[j] = f2bf(w0 * bf2f(u0[j]) + w1 * bf2f(u1[j]) + w2 * bf2f(u2[j]));
                }
            }
            *(uint4*)&As[row * 64 + ((c8 ^ (row & 7)) << 3)] = va.v;
        }
#pragma unroll
        for (int it = 0; it < 8; ++it) {
            int idx = it * 256 + tid, row = idx >> 3, c8 = idx & 7;
            uint4 vb = *(const uint4*)(W + (size_t)row * KIN + kc * 64 + c8 * 8);
            *(uint4*)&Bs[row * 64 + ((c8 ^ (row & 7)) << 3)] = vb;
        }
        __syncthreads();
#pragma unroll
        for (int ks8 = 0; ks8 < 2; ++ks8) {
            bf16x8 af[4], bfr[4];
#pragma unroll
            for (int mi = 0; mi < 4; ++mi) {
                int ra = mi * 16 + lr;
                af[mi] = *(const bf16x8*)&As[ra * 64 + ((((ks8 << 2) + quad) ^ (ra & 7)) << 3)];
            }
#pragma unroll
            for (int ni = 0; ni < 4; ++ni) {
                int rb = wn * 64 + ni * 16 + lr;
                bfr[ni] = *(const bf16x8*)&Bs[rb * 64 + ((((ks8 << 2) + quad) ^ (rb & 7)) << 3)];
            }
#pragma unroll
            for (int mi = 0; mi < 4; ++mi)
#pragma unroll
                for (int ni = 0; ni < 4; ++ni)
                    acc[mi][ni] = __builtin_amdgcn_mfma_f32_16x16x32_bf16(af[mi], bfr[ni], acc[mi][ni], 0, 0, 0);
        }
    }

    float p1a[4] = {0, 0, 0, 0}, p2a[4] = {0, 0, 0, 0};
#pragma unroll
    for (int mi = 0; mi < 4; ++mi)
#pragma unroll
        for (int ni = 0; ni < 4; ++ni)
#pragma unroll
            for (int r = 0; r < 4; ++r) {
                float v = acc[mi][ni][r];
                int row = l0 + mi * 16 + quad * 4 + r;
                int col = wn * 64 + ni * 16 + lr;
                Out[(size_t)row * OC + col] = f2bf(v);
                p1a[ni] += v; p2a[ni] += v * v;
            }
    sS1[tid] = 0.f; sS2[tid] = 0.f;
    __syncthreads();
#pragma unroll
    for (int ni = 0; ni < 4; ++ni) {
        atomicAdd(&sS1[wn * 64 + ni * 16 + lr], p1a[ni]);
        atomicAdd(&sS2[wn * 64 + ni * 16 + lr], p2a[ni]);
    }
    __syncthreads();
    atomicAdd(&S1[tid], sS1[tid]);
    atomicAdd(&S2[tid], sS2[tid]);
}

// ---------------- GEMM2/3: C = act(A)*W^T + stats; BN coeffs computed inline ----------------
template <int K>
__global__ __launch_bounds__(256) void k_gemm(const unsigned short* __restrict__ A,
                                              const unsigned short* __restrict__ W,
                                              unsigned short* __restrict__ Out,
                                              float* __restrict__ S1, float* __restrict__ S2,
                                              const float* __restrict__ S1in,
                                              const float* __restrict__ S2in,
                                              const void* __restrict__ g_,
                                              const void* __restrict__ bt_,
                                              const int* __restrict__ dflag) {
    __shared__ alignas(16) unsigned short As[64 * 64];
    __shared__ alignas(16) unsigned short Bs[256 * 64];
    __shared__ float sS1[256], sS2[256];
    __shared__ float sCA[256], sCC[256];

    int tid = threadIdx.x;
    int l0 = blockIdx.x * 64;
    int wn = tid >> 6, lane = tid & 63, quad = lane >> 4, lr = lane & 15;

    {
        float m = S1in[tid] * (1.0f / (float)L);
        float var = S2in[tid] * (1.0f / (float)L) - m * m;
        float g, bt;
        if (*dflag) { g = ((const float*)g_)[tid]; bt = ((const float*)bt_)[tid]; }
        else { g = bf2f(((const unsigned short*)g_)[tid]); bt = bf2f(((const unsigned short*)bt_)[tid]); }
        float a = g * rsqrtf(var + BN_EPS);
        sCA[tid] = a;
        sCC[tid] = bt - m * a;
    }

    floatx4 acc[4][4];
#pragma unroll
    for (int mi = 0; mi < 4; ++mi)
#pragma unroll
        for (int ni = 0; ni < 4; ++ni) acc[mi][ni] = (floatx4){0.f, 0.f, 0.f, 0.f};

    constexpr int KC = K / 64;
    for (int kc = 0; kc < KC; ++kc) {
        __syncthreads();
#pragma unroll
        for (int it = 0; it < 2; ++it) {
            int idx = it * 256 + tid, row = idx >> 3, c8 = idx & 7;
            union { uint4 v; unsigned short u[8]; } va;
            va.v = *(const uint4*)(A + (size_t)(l0 + row) * K + kc * 64 + c8 * 8);
            int kb = kc * 64 + c8 * 8;
#pragma unroll
            for (int j = 0; j < 8; ++j) {
                float f = bf2f(va.u[j]);
                va.u[j] = f2bf(gelu_f(sCA[kb + j] * f + sCC[kb + j]));
            }
            *(uint4*)&As[row * 64 + ((c8 ^ (row & 7)) << 3)] = va.v;
        }
#pragma unroll
        for (int it = 0; it < 8; ++it) {
            int idx = it * 256 + tid, row = idx >> 3, c8 = idx & 7;
            uint4 vb = *(const uint4*)(W + (size_t)row * K + kc * 64 + c8 * 8);
            *(uint4*)&Bs[row * 64 + ((c8 ^ (row & 7)) << 3)] = vb;
        }
        __syncthreads();
#pragma unroll
        for (int ks8 = 0; ks8 < 2; ++ks8) {
            bf16x8 af[4], bfr[4];
#pragma unroll
            for (int mi = 0; mi < 4; ++mi) {
                int ra = mi * 16 + lr;
                af[mi] = *(const bf16x8*)&As[ra * 64 + ((((ks8 << 2) + quad) ^ (ra & 7)) << 3)];
            }
#pragma unroll
            for (int ni = 0; ni < 4; ++ni) {
                int rb = wn * 64 + ni * 16 + lr;
                bfr[ni] = *(const bf16x8*)&Bs[rb * 64 + ((((ks8 << 2) + quad) ^ (rb & 7)) << 3)];
            }
#pragma unroll
            for (int mi = 0; mi < 4; ++mi)
#pragma unroll
                for (int ni = 0; ni < 4; ++ni)
                    acc[mi][ni] = __builtin_amdgcn_mfma_f32_16x16x32_bf16(af[mi], bfr[ni], acc[mi][ni], 0, 0, 0);
        }
    }

    float p1a[4] = {0, 0, 0, 0}, p2a[4] = {0, 0, 0, 0};
#pragma unroll
    for (int mi = 0; mi < 4; ++mi)
#pragma unroll
        for (int ni = 0; ni < 4; ++ni)
#pragma unroll
            for (int r = 0; r < 4; ++r) {
                float v = acc[mi][ni][r];
                int row = l0 + mi * 16 + quad * 4 + r;
                int col = wn * 64 + ni * 16 + lr;
                Out[(size_t)row * OC + col] = f2bf(v);
                p1a[ni] += v; p2a[ni] += v * v;
            }
    sS1[tid] = 0.f; sS2[tid] = 0.f;
    __syncthreads();
#pragma unroll
    for (int ni = 0; ni < 4; ++ni) {
        atomicAdd(&sS1[wn * 64 + ni * 16 + lr], p1a[ni]);
        atomicAdd(&sS2[wn * 64 + ni * 16 + lr], p2a[ni]);
    }
    __syncthreads();
    atomicAdd(&S1[tid], sS1[tid]);
    atomicAdd(&S2[tid], sS2[tid]);
}

// ---------------- launch 5: out = gelu( bn2(t2) + gelu(bn0(t0)) ); BN coeffs inline ----------------
__global__ __launch_bounds__(256) void k_final(const unsigned short* __restrict__ t0,
                                               const unsigned short* __restrict__ t2,
                                               const float* __restrict__ S1_0, const float* __restrict__ S2_0,
                                               const float* __restrict__ S1_2, const float* __restrict__ S2_2,
                                               const void* __restrict__ g0_, const void* __restrict__ bt0_,
                                               const void* __restrict__ g2_, const void* __restrict__ bt2_,
                                               const int* __restrict__ dflag,
                                               void* __restrict__ out_) {
    __shared__ float sA0[256], sC0[256], sA2[256], sC2[256];
    int tid = threadIdx.x;
    bool isf = (*dflag != 0);
    {
        float m0 = S1_0[tid] * (1.0f / (float)L);
        float v0_ = S2_0[tid] * (1.0f / (float)L) - m0 * m0;
        float m2 = S1_2[tid] * (1.0f / (float)L);
        float v2_ = S2_2[tid] * (1.0f / (float)L) - m2 * m2;
        float g0, b0, g2, b2;
        if (isf) {
            g0 = ((const float*)g0_)[tid]; b0 = ((const float*)bt0_)[tid];
            g2 = ((const float*)g2_)[tid]; b2 = ((const float*)bt2_)[tid];
        } else {
            g0 = bf2f(((const unsigned short*)g0_)[tid]); b0 = bf2f(((const unsigned short*)bt0_)[tid]);
            g2 = bf2f(((const unsigned short*)g2_)[tid]); b2 = bf2f(((const unsigned short*)bt2_)[tid]);
        }
        float a0 = g0 * rsqrtf(v0_ + BN_EPS);
        float a2 = g2 * rsqrtf(v2_ + BN_EPS);
        sA0[tid] = a0; sC0[tid] = b0 - m0 * a0;
        sA2[tid] = a2; sC2[tid] = b2 - m2 * a2;
    }
    __syncthreads();

    int idx = (blockIdx.x * 256 + tid) * 8;
    int col = idx & (OC - 1);
    union { uint4 v; unsigned short u[8]; } v0, v2;
    v0.v = *(const uint4*)(t0 + idx);
    v2.v = *(const uint4*)(t2 + idx);
    float r[8];
#pragma unroll
    for (int j = 0; j < 8; ++j) {
        float x = gelu_f(sA0[col + j] * bf2f(v0.u[j]) + sC0[col + j]);
        float y = sA2[col + j] * bf2f(v2.u[j]) + sC2[col + j];
        r[j] = gelu_f(x + y);
    }
    if (isf) {
        float* o = (float*)out_ + idx;
        float4 lo = {r[0], r[1], r[2], r[3]};
        float4 hi = {r[4], r[5], r[6], r[7]};
        *(float4*)o = lo;
        *(float4*)(o + 4) = hi;
    } else {
        union { uint4 v; unsigned short u[8]; } vo;
#pragma unroll
        for (int j = 0; j < 8; ++j) vo.u[j] = f2bf(r[j]);
        *(uint4*)((unsigned short*)out_ + idx) = vo.v;
    }
}

extern "C" void kernel_launch(void* const* d_in, const int* in_sizes, int n_in,
                              void* d_out, int out_size, void* d_ws, size_t ws_size,
                              hipStream_t stream) {
    const void* xyz1    = d_in[0];
    const void* xyz2    = d_in[1];
    const void* points1 = d_in[2];
    const void* points2 = d_in[3];
    const void* W_fuse  = d_in[4];
    const void* g_fuse  = d_in[6];
    const void* bt_fuse = d_in[7];
    const void* W1      = d_in[8];
    const void* g1      = d_in[10];
    const void* bt1     = d_in[11];
    const void* W2      = d_in[12];
    const void* g2      = d_in[14];
    const void* bt2     = d_in[15];

    char* ws = (char*)d_ws;
    unsigned short* t2 = (unsigned short*)ws;               // 16.8 MB (old X region)
    unsigned short* t0 = (unsigned short*)(ws + 25165824);
    unsigned short* t1 = (unsigned short*)d_out;            // d_out as bf16 scratch until k_final
    int*   nn_idx = (int*)(ws + 41943040);
    float* nn_w   = (float*)(ws + 42336256);
    float* stats  = (float*)(ws + 42729472);
    int*   dflag  = (int*)(ws + 42729472 + 3072 * 4);
    unsigned short* Wbf = (unsigned short*)(ws + 42745856); // Wf | W1 | W2 contiguous

    float *S1_0 = stats,        *S2_0 = stats + 256;
    float *S1_1 = stats + 512,  *S2_1 = stats + 768;
    float *S1_2 = stats + 1024, *S2_2 = stats + 1280;

    // launch 1: zero-stats + weight prep + 3-NN
    k_front<<<1926, 256, 0, stream>>>(xyz1, xyz2, W_fuse, W1, W2, Wbf, stats, dflag, nn_idx, nn_w);
    // launch 2: GEMM1 with fused interp/concat (X never materialized)
    k_gemm1<<<L / 64, 256, 0, stream>>>(points1, points2, nn_idx, nn_w, dflag,
                                        Wbf, t0, S1_0, S2_0);
    // launches 3-4: GEMM2/3 with BN+gelu staging
    k_gemm<OC><<<L / 64, 256, 0, stream>>>(t0, Wbf + 98304, t1, S1_1, S2_1,
                                           S1_0, S2_0, g_fuse, bt_fuse, dflag);
    k_gemm<OC><<<L / 64, 256, 0, stream>>>(t1, Wbf + 163840, t2, S1_2, S2_2,
                                           S1_1, S2_1, g1, bt1, dflag);
    // launch 5: final elementwise
    k_final<<<L * OC / (256 * 8), 256, 0, stream>>>(t0, t2, S1_0, S2_0, S1_2, S2_2,
                                                    g_fuse, bt_fuse, g2, bt2, dflag, d_out);
}

// Round 2
// 229.121 us; speedup vs baseline: 1.0103x; 1.0103x over previous
//
#include <hip/hip_runtime.h>
#include <hip/hip_bf16.h>

// Problem constants
constexpr int Bb = 8, Nn = 4096, Ss = 1024;
constexpr int D1 = 128, D2 = 256, KIN = 384, OC = 256;
constexpr int L = Bb * Nn;             // 32768 rows
constexpr float BN_EPS = 1e-5f;

typedef __attribute__((ext_vector_type(4))) float floatx4;
typedef __attribute__((ext_vector_type(8))) __bf16 bf16x8;

#define DEV __device__ __forceinline__

DEV float bf2f(unsigned short u) {
    union { unsigned int i; float f; } v; v.i = ((unsigned int)u) << 16; return v.f;
}
DEV unsigned short f2bf(float f) {
    union { float f; unsigned int i; } v; v.f = f;
    unsigned int x = v.i;
    return (unsigned short)((x + 0x7FFFu + ((x >> 16) & 1u)) >> 16);  // RNE
}
// Fast tanh-form gelu: x*sigmoid(2u), u = sqrt(2/pi)*(x+0.044715x^3).
DEV float gelu_f(float x) {
    float u = x * (0.7978845608f + 0.0356774081f * x * x);
    float t = __expf(-2.0f * u);
    return x * __builtin_amdgcn_rcpf(1.0f + t);
}

// Per-block dtype probe (f32 low-halves are mantissa junk; bf16 pairs are sane).
DEV bool probe_isf(const unsigned int* __restrict__ w, int tid) {
    unsigned int lo = w[tid & 63] & 0xFFFFu;
    int e = (int)((lo >> 7) & 0xFF);
    unsigned long long m = __ballot(e >= 100 && e <= 144);
    return __popcll(m) < 48;
}

// Weight-prep permutation: Wbf is stored PRE-SWIZZLED so GEMM B-staging can
// global_load_lds linearly while swizzled ds_read fragment indexing stays valid.
// Layout: perm[row*K + kc*64 + c8*8 + j] = orig[row*K + kc*64 + (c8^(row&7))*8 + j].
template <int K> DEV int permoff(int off) {
    int row = off / K, rr = off - row * K;
    int cg = (rr >> 3) & 7;
    return row * K + (rr & ~63) + (((cg ^ (row & 7)) << 3)) + (rr & 7);
}

// Branchless merge of two sorted (asc) top-3 lists; pref=true -> ties keep "a".
DEV void merge3(float& d0, float& d1, float& d2, int& i0, int& i1, int& i2,
                float e0, float e1, float e2, int j0, int j1, int j2, bool pref) {
    float a0 = d0, a1 = d1, a2 = d2; int x0 = i0, x1 = i1, x2 = i2;
    float b0 = e0, b1 = e1;          int y0 = j0, y1 = j1;
    bool t = pref ? (a0 <= b0) : (a0 < b0);
    d0 = t ? a0 : b0; i0 = t ? x0 : y0;
    a0 = t ? a1 : a0; x0 = t ? x1 : x0;
    a1 = t ? a2 : a1; x1 = t ? x2 : x1;
    b0 = t ? b0 : b1; y0 = t ? y0 : y1;
    b1 = t ? b1 : e2; y1 = t ? y1 : j2;
    t = pref ? (a0 <= b0) : (a0 < b0);
    d1 = t ? a0 : b0; i1 = t ? x0 : y0;
    a0 = t ? a1 : a0; x0 = t ? x1 : x0;
    b0 = t ? b0 : b1; y0 = t ? y0 : y1;
    t = pref ? (a0 <= b0) : (a0 < b0);
    d2 = t ? a0 : b0; i2 = t ? x0 : y0;
}

// ---------------- launch 1: zero-stats | prep-weights | 3-NN ----------------
__global__ __launch_bounds__(256) void k_front(const void* __restrict__ xyz1_,
                                               const void* __restrict__ xyz2_,
                                               const void* __restrict__ w0_,
                                               const void* __restrict__ w1_,
                                               const void* __restrict__ w2_,
                                               unsigned short* __restrict__ Wdst,
                                               float* __restrict__ stats,
                                               int* __restrict__ dflag,
                                               int* __restrict__ nn_idx,
                                               float* __restrict__ nn_w) {
    int tid = threadIdx.x;
    int bid = blockIdx.x;
    bool isf = probe_isf((const unsigned int*)xyz1_, tid);

    if (bid < 6) {
        stats[bid * 256 + tid] = 0.0f;
        if (bid == 0 && tid == 0) *dflag = isf ? 1 : 0;
        return;
    }
    if (bid < 902) {
        int i = (bid - 6) * 256 + tid;
        const void* src; int off;
        if (i < 98304)       { src = w0_; off = permoff<384>(i); }
        else if (i < 163840) { src = w1_; off = permoff<256>(i - 98304); }
        else                 { src = w2_; off = permoff<256>(i - 163840); }
        Wdst[i] = isf ? f2bf(((const float*)src)[off]) : ((const unsigned short*)src)[off];
        return;
    }

    __shared__ alignas(16) float s4[Ss * 4 + 32];
    int bn0 = (bid - 902) * 32;
    int b = bn0 >> 12;

    if (isf) {
        const float* p2 = (const float*)xyz2_ + (size_t)b * Ss * 3;
        for (int i = tid; i < Ss * 3; i += 256) {
            int s = i / 3, k = i - s * 3;
            s4[s * 4 + k + ((s >> 7) << 2)] = p2[i];
        }
    } else {
        const unsigned short* p2 = (const unsigned short*)xyz2_ + (size_t)b * Ss * 3;
        for (int i = tid; i < Ss * 3; i += 256) {
            int s = i / 3, k = i - s * 3;
            s4[s * 4 + k + ((s >> 7) << 2)] = bf2f(p2[i]);
        }
    }
    __syncthreads();
    for (int s = tid; s < Ss; s += 256) {
        int a = s * 4 + ((s >> 7) << 2);
        float x = s4[a], y = s4[a + 1], z = s4[a + 2];
        s4[a + 3] = x * x + y * y + z * z;
    }
    __syncthreads();

    int part = tid & 7;
    int bn = bn0 + (tid >> 3);
    float x1, y1, z1;
    if (isf) {
        const float* p1 = (const float*)xyz1_ + (size_t)bn * 3;
        x1 = p1[0]; y1 = p1[1]; z1 = p1[2];
    } else {
        const unsigned short* p1 = (const unsigned short*)xyz1_ + (size_t)bn * 3;
        x1 = bf2f(p1[0]); y1 = bf2f(p1[1]); z1 = bf2f(p1[2]);
    }
    float n1 = x1 * x1 + y1 * y1 + z1 * z1;

    float d0 = 3.4e38f, d1 = 3.4e38f, d2 = 3.4e38f;
    int i0 = 0, i1 = 0, i2 = 0;
    const float* sp = &s4[part * 516];
#pragma unroll 4
    for (int j = 0; j < 128; ++j) {
        float4 qv = *(const float4*)(sp + j * 4);
        float d = n1 + qv.w - 2.0f * (x1 * qv.x + y1 * qv.y + z1 * qv.z);
        int s = part * 128 + j;
        bool c2 = d < d2, c1 = d < d1, c0 = d < d0;
        d2 = c1 ? d1 : (c2 ? d : d2); i2 = c1 ? i1 : (c2 ? s : i2);
        d1 = c0 ? d0 : (c1 ? d : d1); i1 = c0 ? i0 : (c1 ? s : i1);
        d0 = c0 ? d  : d0;            i0 = c0 ? s  : i0;
    }
#pragma unroll
    for (int m = 1; m <= 4; m <<= 1) {
        float e0 = __shfl_xor(d0, m, 64), e1 = __shfl_xor(d1, m, 64), e2 = __shfl_xor(d2, m, 64);
        int   j0 = __shfl_xor(i0, m, 64), j1 = __shfl_xor(i1, m, 64), j2 = __shfl_xor(i2, m, 64);
        bool pref = (part < (part ^ m));
        merge3(d0, d1, d2, i0, i1, i2, e0, e1, e2, j0, j1, j2, pref);
    }
    if (part == 0) {
        float r0 = 1.0f / (d0 + 1e-8f), r1 = 1.0f / (d1 + 1e-8f), r2 = 1.0f / (d2 + 1e-8f);
        float rs = 1.0f / (r0 + r1 + r2);
        nn_idx[bn * 3 + 0] = i0; nn_idx[bn * 3 + 1] = i1; nn_idx[bn * 3 + 2] = i2;
        nn_w[bn * 3 + 0] = r0 * rs; nn_w[bn * 3 + 1] = r1 * rs; nn_w[bn * 3 + 2] = r2 * rs;
    }
}

// ---------------- launch 2: GEMM1 with A built on the fly ----------------
// B staged via global_load_lds (W pre-swizzled); glds issued first so L2
// latency hides under the interp/convert VALU of the A-build.
__global__ __launch_bounds__(256) void k_gemm1(const void* __restrict__ p1_,
                                               const void* __restrict__ p2_,
                                               const int* __restrict__ nn_idx,
                                               const float* __restrict__ nn_w,
                                               const int* __restrict__ dflag,
                                               const unsigned short* __restrict__ W,
                                               unsigned short* __restrict__ Out,
                                               float* __restrict__ S1, float* __restrict__ S2) {
    __shared__ alignas(16) unsigned short As[64 * 64];
    __shared__ alignas(16) unsigned short Bs[256 * 64];
    __shared__ float sS1[256], sS2[256];

    int tid = threadIdx.x;
    int l0 = blockIdx.x * 64;
    int wn = tid >> 6, lane = tid & 63, quad = lane >> 4, lr = lane & 15;
    bool isf = (*dflag != 0);

    floatx4 acc[4][4];
#pragma unroll
    for (int mi = 0; mi < 4; ++mi)
#pragma unroll
        for (int ni = 0; ni < 4; ++ni) acc[mi][ni] = (floatx4){0.f, 0.f, 0.f, 0.f};

    for (int kc = 0; kc < KIN / 64; ++kc) {
        __syncthreads();
        // B: direct-to-LDS, linear dest (W pre-swizzled at prep)
#pragma unroll
        for (int it = 0; it < 8; ++it) {
            int chunk = it * 4 + wn;                    // 0..31 (8 rows each)
            int row = chunk * 8 + (lane >> 3);
            int cg = lane & 7;
            const unsigned short* src = W + (size_t)row * KIN + kc * 64 + cg * 8;
            __builtin_amdgcn_global_load_lds(
                (const __attribute__((address_space(1))) void*)src,
                (__attribute__((address_space(3))) void*)&Bs[chunk * 512],
                16, 0, 0);
        }
#pragma unroll
        for (int it = 0; it < 2; ++it) {
            int idx = it * 256 + tid, row = idx >> 3, c8 = idx & 7;
            int pt = l0 + row;
            int c0 = kc * 64 + c8 * 8;
            union { uint4 v; unsigned short u[8]; } va;
            if (c0 < D1) {
                if (isf) {
                    const float* p = (const float*)p1_ + (size_t)pt * D1 + c0;
                    float4 f0 = *(const float4*)p;
                    float4 f1 = *(const float4*)(p + 4);
                    va.u[0] = f2bf(f0.x); va.u[1] = f2bf(f0.y); va.u[2] = f2bf(f0.z); va.u[3] = f2bf(f0.w);
                    va.u[4] = f2bf(f1.x); va.u[5] = f2bf(f1.y); va.u[6] = f2bf(f1.z); va.u[7] = f2bf(f1.w);
                } else {
                    va.v = *(const uint4*)((const unsigned short*)p1_ + (size_t)pt * D1 + c0);
                }
            } else {
                int c2 = c0 - D1;
                int b = pt >> 12;
                int j0 = nn_idx[pt * 3], j1 = nn_idx[pt * 3 + 1], j2 = nn_idx[pt * 3 + 2];
                float w0 = nn_w[pt * 3], w1 = nn_w[pt * 3 + 1], w2 = nn_w[pt * 3 + 2];
                if (isf) {
                    const float* base = (const float*)p2_;
                    const float* r0 = base + ((size_t)(b * Ss + j0)) * D2 + c2;
                    const float* r1 = base + ((size_t)(b * Ss + j1)) * D2 + c2;
                    const float* r2 = base + ((size_t)(b * Ss + j2)) * D2 + c2;
#pragma unroll
                    for (int h = 0; h < 2; ++h) {
                        float4 a0 = *(const float4*)(r0 + h * 4);
                        float4 a1 = *(const float4*)(r1 + h * 4);
                        float4 a2 = *(const float4*)(r2 + h * 4);
                        va.u[h * 4 + 0] = f2bf(w0 * a0.x + w1 * a1.x + w2 * a2.x);
                        va.u[h * 4 + 1] = f2bf(w0 * a0.y + w1 * a1.y + w2 * a2.y);
                        va.u[h * 4 + 2] = f2bf(w0 * a0.z + w1 * a1.z + w2 * a2.z);
                        va.u[h * 4 + 3] = f2bf(w0 * a0.w + w1 * a1.w + w2 * a2.w);
                    }
                } else {
                    const unsigned short* base = (const unsigned short*)p2_;
                    uint4 v0 = *(const uint4*)(base + ((size_t)(b * Ss + j0)) * D2 + c2);
                    uint4 v1 = *(const uint4*)(base + ((size_t)(b * Ss + j1)) * D2 + c2);
                    uint4 v2 = *(const uint4*)(base + ((size_t)(b * Ss + j2)) * D2 + c2);
                    const unsigned short* u0 = (const unsigned short*)&v0;
                    const unsigned short* u1 = (const unsigned short*)&v1;
                    const unsigned short* u2 = (const unsigned short*)&v2;
#pragma unroll
                    for (int j = 0; j < 8; ++j)
                        va.u[j] = f2bf(w0 * bf2f(u0[j]) + w1 * bf2f(u1[j]) + w2 * bf2f(u2[j]));
                }
            }
            *(uint4*)&As[row * 64 + ((c8 ^ (row & 7)) << 3)] = va.v;
        }
        __syncthreads();   // drains vmcnt (glds) + lgkm (As writes)
#pragma unroll
        for (int ks8 = 0; ks8 < 2; ++ks8) {
            bf16x8 af[4], bfr[4];
#pragma unroll
            for (int mi = 0; mi < 4; ++mi) {
                int ra = mi * 16 + lr;
                af[mi] = *(const bf16x8*)&As[ra * 64 + ((((ks8 << 2) + quad) ^ (ra & 7)) << 3)];
            }
#pragma unroll
            for (int ni = 0; ni < 4; ++ni) {
                int rb = wn * 64 + ni * 16 + lr;
                bfr[ni] = *(const bf16x8*)&Bs[rb * 64 + ((((ks8 << 2) + quad) ^ (rb & 7)) << 3)];
            }
#pragma unroll
            for (int mi = 0; mi < 4; ++mi)
#pragma unroll
                for (int ni = 0; ni < 4; ++ni)
                    acc[mi][ni] = __builtin_amdgcn_mfma_f32_16x16x32_bf16(af[mi], bfr[ni], acc[mi][ni], 0, 0, 0);
        }
    }

    float p1a[4] = {0, 0, 0, 0}, p2a[4] = {0, 0, 0, 0};
#pragma unroll
    for (int mi = 0; mi < 4; ++mi)
#pragma unroll
        for (int ni = 0; ni < 4; ++ni)
#pragma unroll
            for (int r = 0; r < 4; ++r) {
                float v = acc[mi][ni][r];
                int row = l0 + mi * 16 + quad * 4 + r;
                int col = wn * 64 + ni * 16 + lr;
                Out[(size_t)row * OC + col] = f2bf(v);
                p1a[ni] += v; p2a[ni] += v * v;
            }
    sS1[tid] = 0.f; sS2[tid] = 0.f;
    __syncthreads();
#pragma unroll
    for (int ni = 0; ni < 4; ++ni) {
        atomicAdd(&sS1[wn * 64 + ni * 16 + lr], p1a[ni]);
        atomicAdd(&sS2[wn * 64 + ni * 16 + lr], p2a[ni]);
    }
    __syncthreads();
    atomicAdd(&S1[tid], sS1[tid]);
    atomicAdd(&S2[tid], sS2[tid]);
}

// ---------------- GEMM2/3: C = act(A)*W^T + stats ----------------
// A (activated) hoisted to LDS once in the prologue; kc loop stages only B
// via global_load_lds (pre-swizzled W, linear dest) -> loop body is pure
// {glds issue, barrier, ds_read, MFMA, barrier}.
template <int K>
__global__ __launch_bounds__(256) void k_gemm(const unsigned short* __restrict__ A,
                                              const unsigned short* __restrict__ W,
                                              unsigned short* __restrict__ Out,
                                              float* __restrict__ S1, float* __restrict__ S2,
                                              const float* __restrict__ S1in,
                                              const float* __restrict__ S2in,
                                              const void* __restrict__ g_,
                                              const void* __restrict__ bt_,
                                              const int* __restrict__ dflag) {
    __shared__ alignas(16) unsigned short As[64 * K];   // K=256 -> 32 KB, full-K activated A
    __shared__ alignas(16) unsigned short Bs[256 * 64];
    __shared__ float sS1[256], sS2[256];
    __shared__ float sCA[256], sCC[256];

    int tid = threadIdx.x;
    int l0 = blockIdx.x * 64;
    int wn = tid >> 6, lane = tid & 63, quad = lane >> 4, lr = lane & 15;

    {
        float m = S1in[tid] * (1.0f / (float)L);
        float var = S2in[tid] * (1.0f / (float)L) - m * m;
        float g, bt;
        if (*dflag) { g = ((const float*)g_)[tid]; bt = ((const float*)bt_)[tid]; }
        else { g = bf2f(((const unsigned short*)g_)[tid]); bt = bf2f(((const unsigned short*)bt_)[tid]); }
        float a = g * rsqrtf(var + BN_EPS);
        sCA[tid] = a;
        sCC[tid] = bt - m * a;
    }
    __syncthreads();

    // Prologue: stage full activated A tile (swizzled within each 64-col chunk)
#pragma unroll
    for (int it = 0; it < (64 * K / 8) / 256; ++it) {   // K=256 -> 8 iters
        int idx = it * 256 + tid;
        int row = idx >> 5, cg = idx & 31;              // 32 col-groups of 8
        union { uint4 v; unsigned short u[8]; } va;
        va.v = *(const uint4*)(A + (size_t)(l0 + row) * K + cg * 8);
        int kb = cg * 8;
#pragma unroll
        for (int j = 0; j < 8; ++j) {
            float f = bf2f(va.u[j]);
            va.u[j] = f2bf(gelu_f(sCA[kb + j] * f + sCC[kb + j]));
        }
        int sg = (cg & 24) | ((cg & 7) ^ (row & 7));
        *(uint4*)&As[row * K + sg * 8] = va.v;
    }

    floatx4 acc[4][4];
#pragma unroll
    for (int mi = 0; mi < 4; ++mi)
#pragma unroll
        for (int ni = 0; ni < 4; ++ni) acc[mi][ni] = (floatx4){0.f, 0.f, 0.f, 0.f};

    constexpr int KC = K / 64;
    for (int kc = 0; kc < KC; ++kc) {
        __syncthreads();   // prev readers done with Bs; kc=0: As writes ordered too (drain)
#pragma unroll
        for (int it = 0; it < 8; ++it) {
            int chunk = it * 4 + wn;
            int row = chunk * 8 + (lane >> 3);
            int cg = lane & 7;
            const unsigned short* src = W + (size_t)row * K + kc * 64 + cg * 8;
            __builtin_amdgcn_global_load_lds(
                (const __attribute__((address_space(1))) void*)src,
                (__attribute__((address_space(3))) void*)&Bs[chunk * 512],
                16, 0, 0);
        }
        __syncthreads();   // drains vmcnt -> Bs ready
#pragma unroll
        for (int ks8 = 0; ks8 < 2; ++ks8) {
            bf16x8 af[4], bfr[4];
#pragma unroll
            for (int mi = 0; mi < 4; ++mi) {
                int ra = mi * 16 + lr;
                int g = kc * 8 + ((((ks8 << 2) + quad)) ^ (ra & 7));
                af[mi] = *(const bf16x8*)&As[ra * K + g * 8];
            }
#pragma unroll
            for (int ni = 0; ni < 4; ++ni) {
                int rb = wn * 64 + ni * 16 + lr;
                bfr[ni] = *(const bf16x8*)&Bs[rb * 64 + ((((ks8 << 2) + quad) ^ (rb & 7)) << 3)];
            }
#pragma unroll
            for (int mi = 0; mi < 4; ++mi)
#pragma unroll
                for (int ni = 0; ni < 4; ++ni)
                    acc[mi][ni] = __builtin_amdgcn_mfma_f32_16x16x32_bf16(af[mi], bfr[ni], acc[mi][ni], 0, 0, 0);
        }
    }

    float p1a[4] = {0, 0, 0, 0}, p2a[4] = {0, 0, 0, 0};
#pragma unroll
    for (int mi = 0; mi < 4; ++mi)
#pragma unroll
        for (int ni = 0; ni < 4; ++ni)
#pragma unroll
            for (int r = 0; r < 4; ++r) {
                float v = acc[mi][ni][r];
                int row = l0 + mi * 16 + quad * 4 + r;
                int col = wn * 64 + ni * 16 + lr;
                Out[(size_t)row * OC + col] = f2bf(v);
                p1a[ni] += v; p2a[ni] += v * v;
            }
    sS1[tid] = 0.f; sS2[tid] = 0.f;
    __syncthreads();
#pragma unroll
    for (int ni = 0; ni < 4; ++ni) {
        atomicAdd(&sS1[wn * 64 + ni * 16 + lr], p1a[ni]);
        atomicAdd(&sS2[wn * 64 + ni * 16 + lr], p2a[ni]);
    }
    __syncthreads();
    atomicAdd(&S1[tid], sS1[tid]);
    atomicAdd(&S2[tid], sS2[tid]);
}

// ---------------- launch 5: out = gelu( bn2(t2) + gelu(bn0(t0)) ) ----------------
__global__ __launch_bounds__(256) void k_final(const unsigned short* __restrict__ t0,
                                               const unsigned short* __restrict__ t2,
                                               const float* __restrict__ S1_0, const float* __restrict__ S2_0,
                                               const float* __restrict__ S1_2, const float* __restrict__ S2_2,
                                               const void* __restrict__ g0_, const void* __restrict__ bt0_,
                                               const void* __restrict__ g2_, const void* __restrict__ bt2_,
                                               const int* __restrict__ dflag,
                                               void* __restrict__ out_) {
    __shared__ float sA0[256], sC0[256], sA2[256], sC2[256];
    int tid = threadIdx.x;
    bool isf = (*dflag != 0);
    {
        float m0 = S1_0[tid] * (1.0f / (float)L);
        float v0_ = S2_0[tid] * (1.0f / (float)L) - m0 * m0;
        float m2 = S1_2[tid] * (1.0f / (float)L);
        float v2_ = S2_2[tid] * (1.0f / (float)L) - m2 * m2;
        float g0, b0, g2, b2;
        if (isf) {
            g0 = ((const float*)g0_)[tid]; b0 = ((const float*)bt0_)[tid];
            g2 = ((const float*)g2_)[tid]; b2 = ((const float*)bt2_)[tid];
        } else {
            g0 = bf2f(((const unsigned short*)g0_)[tid]); b0 = bf2f(((const unsigned short*)bt0_)[tid]);
            g2 = bf2f(((const unsigned short*)g2_)[tid]); b2 = bf2f(((const unsigned short*)bt2_)[tid]);
        }
        float a0 = g0 * rsqrtf(v0_ + BN_EPS);
        float a2 = g2 * rsqrtf(v2_ + BN_EPS);
        sA0[tid] = a0; sC0[tid] = b0 - m0 * a0;
        sA2[tid] = a2; sC2[tid] = b2 - m2 * a2;
    }
    __syncthreads();

    int idx = (blockIdx.x * 256 + tid) * 8;
    int col = idx & (OC - 1);
    union { uint4 v; unsigned short u[8]; } v0, v2;
    v0.v = *(const uint4*)(t0 + idx);
    v2.v = *(const uint4*)(t2 + idx);
    float r[8];
#pragma unroll
    for (int j = 0; j < 8; ++j) {
        float x = gelu_f(sA0[col + j] * bf2f(v0.u[j]) + sC0[col + j]);
        float y = sA2[col + j] * bf2f(v2.u[j]) + sC2[col + j];
        r[j] = gelu_f(x + y);
    }
    if (isf) {
        float* o = (float*)out_ + idx;
        float4 lo = {r[0], r[1], r[2], r[3]};
        float4 hi = {r[4], r[5], r[6], r[7]};
        *(float4*)o = lo;
        *(float4*)(o + 4) = hi;
    } else {
        union { uint4 v; unsigned short u[8]; } vo;
#pragma unroll
        for (int j = 0; j < 8; ++j) vo.u[j] = f2bf(r[j]);
        *(uint4*)((unsigned short*)out_ + idx) = vo.v;
    }
}

extern "C" void kernel_launch(void* const* d_in, const int* in_sizes, int n_in,
                              void* d_out, int out_size, void* d_ws, size_t ws_size,
                              hipStream_t stream) {
    const void* xyz1    = d_in[0];
    const void* xyz2    = d_in[1];
    const void* points1 = d_in[2];
    const void* points2 = d_in[3];
    const void* W_fuse  = d_in[4];
    const void* g_fuse  = d_in[6];
    const void* bt_fuse = d_in[7];
    const void* W1      = d_in[8];
    const void* g1      = d_in[10];
    const void* bt1     = d_in[11];
    const void* W2      = d_in[12];
    const void* g2      = d_in[14];
    const void* bt2     = d_in[15];

    char* ws = (char*)d_ws;
    unsigned short* t2 = (unsigned short*)ws;               // 16.8 MB (old X region)
    unsigned short* t0 = (unsigned short*)(ws + 25165824);
    unsigned short* t1 = (unsigned short*)d_out;            // d_out as bf16 scratch until k_final
    int*   nn_idx = (int*)(ws + 41943040);
    float* nn_w   = (float*)(ws + 42336256);
    float* stats  = (float*)(ws + 42729472);
    int*   dflag  = (int*)(ws + 42729472 + 3072 * 4);
    unsigned short* Wbf = (unsigned short*)(ws + 42745856); // Wf | W1 | W2 contiguous, PRE-SWIZZLED

    float *S1_0 = stats,        *S2_0 = stats + 256;
    float *S1_1 = stats + 512,  *S2_1 = stats + 768;
    float *S1_2 = stats + 1024, *S2_2 = stats + 1280;

    // launch 1: zero-stats + weight prep (pre-swizzled) + 3-NN
    k_front<<<1926, 256, 0, stream>>>(xyz1, xyz2, W_fuse, W1, W2, Wbf, stats, dflag, nn_idx, nn_w);
    // launch 2: GEMM1 with fused interp/concat (X never materialized)
    k_gemm1<<<L / 64, 256, 0, stream>>>(points1, points2, nn_idx, nn_w, dflag,
                                        Wbf, t0, S1_0, S2_0);
    // launches 3-4: GEMM2/3 with BN+gelu staging
    k_gemm<OC><<<L / 64, 256, 0, stream>>>(t0, Wbf + 98304, t1, S1_1, S2_1,
                                           S1_0, S2_0, g_fuse, bt_fuse, dflag);
    k_gemm<OC><<<L / 64, 256, 0, stream>>>(t1, Wbf + 163840, t2, S1_2, S2_2,
                                           S1_1, S2_1, g1, bt1, dflag);
    // launch 5: final elementwise
    k_final<<<L * OC / (256 * 8), 256, 0, stream>>>(t0, t2, S1_0, S2_0, S1_2, S2_2,
                                                    g_fuse, bt_fuse, g2, bt2, dflag, d_out);
}